// Round 11
// baseline (326.908 us; speedup 1.0000x reference)
//
#include <hip/hip_runtime.h>
#include <hip/hip_bf16.h>
#include <math.h>

#define NL 3000
#define NN 9000
#define NE 200000
#define DD 512
#define SS 128
#define MPAD 9088          // 71 * 128
#define MT   (MPAD/16)     // 568 m-tiles

typedef __attribute__((ext_vector_type(8))) short    bf16x8;
typedef __attribute__((ext_vector_type(8))) ushort   u16x8;
typedef __attribute__((ext_vector_type(4))) float    f32x4;

static __device__ __forceinline__ ushort f2bf(float f){
  unsigned u = __float_as_uint(f);
  return (ushort)((u + 0x7FFFu + ((u>>16)&1u)) >> 16);   // RNE
}
static __device__ __forceinline__ float bf2f(ushort u){
  return __uint_as_float(((unsigned)u)<<16);
}

// ================= merged pack kernel (+ src histogram + row_sum zero) =================
// [0,2272): concat->Apack1 | [2272,3072): wpack5 | [3072,3088): pack_w1 | [3088,3120): zero row_sum + hist cnt
__global__ __launch_bounds__(256) void k_packall(const float* __restrict__ f0, const float* __restrict__ f1,
                        const float* __restrict__ f2, const float* __restrict__ pw,
                        const float* __restrict__ w1,
                        const float* __restrict__ W10, const float* __restrict__ W20,
                        const float* __restrict__ W11, const float* __restrict__ W21,
                        const int* __restrict__ src,
                        short* __restrict__ Ap1, short* __restrict__ BpF,
                        short* __restrict__ Bp10, short* __restrict__ Bp20,
                        short* __restrict__ Bp11, short* __restrict__ Bp21,
                        short* __restrict__ Bpab,
                        float* __restrict__ row_sum, int* __restrict__ cnt){
  int b = blockIdx.x;
  int lane = threadIdx.x & 63;
  if (b < 2272){
    int t = b*4 + (threadIdx.x>>6);
    int tm = t >> 4, tk = t & 15;
    int m = tm*16 + (lane&15);
    int k = tk*32 + (lane>>4)*8;
    float4 v0 = make_float4(0,0,0,0), v1 = v0;
    if (m < NN){
      const float* srow = (m < NL) ? f0 + (size_t)m*DD
                         : (m < 2*NL) ? f1 + (size_t)(m-NL)*DD
                         : f2 + (size_t)(m-2*NL)*DD;
      v0 = *(const float4*)(srow + k);
      v1 = *(const float4*)(srow + k + 4);
    }
    u16x8 r;
    r[0]=f2bf(v0.x); r[1]=f2bf(v0.y); r[2]=f2bf(v0.z); r[3]=f2bf(v0.w);
    r[4]=f2bf(v1.x); r[5]=f2bf(v1.y); r[6]=f2bf(v1.z); r[7]=f2bf(v1.w);
    *(u16x8*)(Ap1 + (size_t)t*512 + lane*8) = r;
  } else if (b < 3072){
    int t = (b-2272)*4 + (threadIdx.x>>6);   // 0..3199
    const float* X; short* P; int K, ntk, lt;
    if (t < 128)      { X=pw;  P=BpF;  K=512;  ntk=16; lt=t; }
    else if (t < 640) { X=W10; P=Bp10; K=512;  ntk=16; lt=t-128; }
    else if (t < 1664){ X=W20; P=Bp20; K=1024; ntk=32; lt=t-640; }
    else if (t < 2176){ X=W11; P=Bp11; K=512;  ntk=16; lt=t-1664; }
    else              { X=W21; P=Bp21; K=1024; ntk=32; lt=t-2176; }
    int tm = lt/ntk, tk = lt - tm*ntk;
    int m = tm*16 + (lane&15);
    int k = tk*32 + (lane>>4)*8;
    float4 v0 = *(const float4*)(X + (size_t)m*K + k);
    float4 v1 = *(const float4*)(X + (size_t)m*K + k + 4);
    u16x8 r;
    r[0]=f2bf(v0.x); r[1]=f2bf(v0.y); r[2]=f2bf(v0.z); r[3]=f2bf(v0.w);
    r[4]=f2bf(v1.x); r[5]=f2bf(v1.y); r[6]=f2bf(v1.z); r[7]=f2bf(v1.w);
    *(u16x8*)(P + (size_t)lt*512 + lane*8) = r;
  } else if (b < 3088){
    int t = (b-3072)*4 + (threadIdx.x>>6);   // 64 tiles: tn*4+tk
    int tn = t >> 2, tk = t & 3;
    int n = tn*16 + (lane&15);
    int k = tk*32 + (lane>>4)*8;
    const float* sp = (n<128) ? (w1 + (size_t)n*256 + k) : (w1 + (size_t)(n-128)*256 + 128 + k);
    float4 v0 = *(const float4*)sp;
    float4 v1 = *(const float4*)(sp+4);
    u16x8 r;
    r[0]=f2bf(v0.x); r[1]=f2bf(v0.y); r[2]=f2bf(v0.z); r[3]=f2bf(v0.w);
    r[4]=f2bf(v1.x); r[5]=f2bf(v1.y); r[6]=f2bf(v1.z); r[7]=f2bf(v1.w);
    *(u16x8*)(Bpab + (size_t)t*512 + lane*8) = r;
  } else {
    int idx = (b-3088)*256 + threadIdx.x;    // 8192 threads
    for (int i=idx; i<NN; i+=8192) row_sum[i]=0.f;
    for (int e=idx; e<NE; e+=8192) atomicAdd(&cnt[src[e]],1);
  }
}

// ---------------- pack fp32 (M,K) row-major -> MFMA-tile bf16 layout ----------------
__global__ __launch_bounds__(256) void k_pack(const float* __restrict__ X, short* __restrict__ P,
                                              int M, int K, int nTilesK){
  int t = blockIdx.x*4 + (threadIdx.x>>6);
  int lane = threadIdx.x & 63;
  int tm = t / nTilesK, tk = t - tm*nTilesK;
  int m = tm*16 + (lane&15);
  int k = tk*32 + (lane>>4)*8;
  float4 v0 = make_float4(0,0,0,0), v1 = v0;
  if (m < M){
    v0 = *(const float4*)(X + (size_t)m*K + k);
    v1 = *(const float4*)(X + (size_t)m*K + k + 4);
  }
  u16x8 r;
  r[0]=f2bf(v0.x); r[1]=f2bf(v0.y); r[2]=f2bf(v0.z); r[3]=f2bf(v0.w);
  r[4]=f2bf(v1.x); r[5]=f2bf(v1.y); r[6]=f2bf(v1.z); r[7]=f2bf(v1.w);
  *(u16x8*)(P + (size_t)t*512 + lane*8) = r;
}

// ================= MFMA GEMM, barrier-free, 128x128 tile, XCD-aware remap =================
// 1-D grid, (N/128)*72 blocks. r=l&7, tt=l>>3, q=tt%9, x=tt/9, y=8q+r (skip y>=71).
// All x-blocks of row-panel y land on the same XCD -> A-panel L2 reuse.
template<int ACT, int OBF>
__global__ __launch_bounds__(256) void k_gmm(const short* __restrict__ Ap, const short* __restrict__ Bp,
                                             void* __restrict__ Cv, int M, int N, int K){
  int l = blockIdx.x;
  int rr = l & 7, tt = l >> 3;
  int q = tt % 9, x = tt / 9;
  int y = q*8 + rr;
  if (y >= 71) return;
  int lane = threadIdx.x & 63, wave = threadIdx.x >> 6;
  int ktiles = K >> 5;
  int bm = y*128 + wave*32;
  int bn = x*128;
  const bf16x8* a0 = (const bf16x8*)(Ap + ((size_t)((bm>>4)  ) * ktiles)*512 + lane*8);
  const bf16x8* a1 = (const bf16x8*)(Ap + ((size_t)((bm>>4)+1) * ktiles)*512 + lane*8);
  const bf16x8* bp[8];
  #pragma unroll
  for (int i=0;i<8;++i)
    bp[i] = (const bf16x8*)(Bp + ((size_t)((bn>>4)+i) * ktiles)*512 + lane*8);
  f32x4 acc[2][8];
  #pragma unroll
  for (int i=0;i<2;++i)
    #pragma unroll
    for (int j=0;j<8;++j) acc[i][j] = (f32x4){0.f,0.f,0.f,0.f};

  for (int kt=0; kt<ktiles; ++kt){
    int off = kt*64;
    bf16x8 A0 = a0[off], A1 = a1[off];
    bf16x8 Bf[8];
    #pragma unroll
    for (int i=0;i<8;++i) Bf[i] = bp[i][off];
    #pragma unroll
    for (int i=0;i<8;++i){
      acc[0][i] = __builtin_amdgcn_mfma_f32_16x16x32_bf16(A0, Bf[i], acc[0][i], 0,0,0);
      acc[1][i] = __builtin_amdgcn_mfma_f32_16x16x32_bf16(A1, Bf[i], acc[1][i], 0,0,0);
    }
  }
  int colo = lane & 15;
  int rowo = (lane >> 4) * 4;
  #pragma unroll
  for (int mi=0; mi<2; ++mi){
    #pragma unroll
    for (int r=0; r<4; ++r){
      int row = bm + mi*16 + rowo + r;
      if (row < M){
        #pragma unroll
        for (int ni=0; ni<8; ++ni){
          float v = acc[mi][ni][r];
          if (ACT) v = v>0.f ? v : 0.01f*v;
          int cidx = bn + ni*16 + colo;
          if (OBF) ((ushort*)Cv)[(size_t)row*N + cidx] = f2bf(v);
          else     ((float*) Cv)[(size_t)row*N + cidx] = v;
        }
      }
    }
  }
}

// ---------------- l2norm rows of (NN,128) fp32 -> packed MFMA tiles (K=128) ----------------
__global__ __launch_bounds__(256) void k_l2n(const float* __restrict__ X, short* __restrict__ ShP){
  int lane = threadIdx.x & 63, wave = threadIdx.x >> 6;
  int m = blockIdx.x*4 + wave;
  float2 v = ((const float2*)(X + (size_t)m*SS))[lane];
  float ss = v.x*v.x + v.y*v.y;
  #pragma unroll
  for (int o=32;o>0;o>>=1) ss += __shfl_xor(ss, o);
  float inv = 1.f / fmaxf(sqrtf(ss), 1e-12f);
  int k = 2*lane;
  int tIdx = (m>>4)*4 + (k>>5);
  int pos  = ((m&15) + ((k>>3)&3)*16)*8 + (k&7);
  ushort2 r; r.x = f2bf(v.x*inv); r.y = f2bf(v.y*inv);
  *(ushort2*)(ShP + (size_t)tIdx*512 + pos) = r;
}

// ---------------- per-edge weight + direct CSR scatter: 4 edges/wave, 16 lanes/edge ----------------
__global__ __launch_bounds__(256) void k_edge(const int* __restrict__ src, const int* __restrict__ tgt,
                      const ushort* __restrict__ AB,
                      const float* __restrict__ b1, const float* __restrict__ w2,
                      const float* __restrict__ b2p,
                      const int* __restrict__ row_ptr, int* __restrict__ fill,
                      int* __restrict__ col, float* __restrict__ ewC,
                      float* __restrict__ row_sum){
  int lane = threadIdx.x & 63;
  int p = lane & 15, g = lane >> 4;
  int wid = blockIdx.x*(blockDim.x>>6) + (threadIdx.x>>6);
  int nw  = gridDim.x*(blockDim.x>>6);
  float4 b1a = ((const float4*)b1)[p*2], b1b = ((const float4*)b1)[p*2+1];
  float4 w2a = ((const float4*)w2)[p*2], w2b = ((const float4*)w2)[p*2+1];
  float bb[8] = {b1a.x,b1a.y,b1a.z,b1a.w,b1b.x,b1b.y,b1b.z,b1b.w};
  float ww[8] = {w2a.x,w2a.y,w2a.z,w2a.w,w2b.x,w2b.y,w2b.z,w2b.w};
  float b2 = b2p[0];
  for (int e = wid*4+g; e < NE; e += nw*4){
    int s = src[e], tg_ = tgt[e];
    u16x8 av = *(const u16x8*)(AB + (size_t)s*256 + p*8);
    u16x8 bv = *(const u16x8*)(AB + (size_t)tg_*256 + 128 + p*8);
    float acc = 0.f;
    #pragma unroll
    for (int i=0;i<8;++i){
      float h = bf2f(av[i]) + bf2f(bv[i]) + bb[i];
      h = h>0.f ? h : 0.01f*h;
      acc += h*ww[i];
    }
    acc += __shfl_xor(acc,1); acc += __shfl_xor(acc,2);
    acc += __shfl_xor(acc,4); acc += __shfl_xor(acc,8);
    if (p==0){
      float wgt = 1.f/(1.f+expf(-(acc+b2)));
      int pos = atomicAdd(&fill[s],1);
      int idx = row_ptr[s]+pos;
      col[idx]=tg_;
      ewC[idx]=wgt;
      atomicAdd(&row_sum[s], wgt);
    }
  }
}

// ---------------- shuffle-based scan: cnt -> row_ptr ; zero fill ----------------
__global__ __launch_bounds__(1024) void k_scan(const int* __restrict__ cnt,
                      int* __restrict__ row_ptr, int* __restrict__ fill){
  __shared__ int wsum[16];
  int t = threadIdx.x;
  int lane = t & 63, wid = t >> 6;
  const int CH = 9;                       // 1024*9 = 9216 >= 9000
  int base = t*CH;
  int v[CH]; int s = 0;
  #pragma unroll
  for (int i=0;i<CH;++i){
    int idx = base+i;
    v[i] = (idx<NN) ? cnt[idx] : 0;
    s += v[i];
  }
  int ps = s;
  #pragma unroll
  for (int o=1;o<64;o<<=1){
    int x = __shfl_up(ps, o);
    if (lane >= o) ps += x;
  }
  if (lane==63) wsum[wid] = ps;
  __syncthreads();
  if (wid==0){
    int wv = (lane<16)? wsum[lane] : 0;
    #pragma unroll
    for (int o=1;o<16;o<<=1){
      int x = __shfl_up(wv, o);
      if (lane>=o) wv += x;
    }
    if (lane<16) wsum[lane]=wv;
  }
  __syncthreads();
  int prefix = (wid>0 ? wsum[wid-1] : 0) + (ps - s);
  #pragma unroll
  for (int i=0;i<CH;++i){
    int idx = base+i;
    if (idx<NN){
      row_ptr[idx] = prefix;
      fill[idx] = 0;
      prefix += v[i];
    }
  }
  if (t==1023) row_ptr[NN] = wsum[15];
}

// ---------------- fused SpMM + cat + pack (dinv on the fly) ----------------
template<int LAYER>
__global__ __launch_bounds__(128) void k_spmm_cat(const int* __restrict__ row_ptr, const int* __restrict__ col,
                     const float* __restrict__ ew, const float* __restrict__ row_sum,
                     const ushort* __restrict__ proj,
                     const float* __restrict__ xf0, const float* __restrict__ xf1,
                     const float* __restrict__ xf2,
                     short* __restrict__ P){
  int m = blockIdx.x, t = threadIdx.x;
  int beg = row_ptr[m], end = row_ptr[m+1];
  float rsm = row_sum[m];
  float dim = rsm>0.f ? rsqrtf(rsm) : 0.f;
  float4 a0 = make_float4(0,0,0,0), a1 = a0, a2 = a0, a3 = a0;
  int j = beg;
  for (; j+4<=end; j+=4){
    int c0=col[j], c1=col[j+1], c2=col[j+2], c3=col[j+3];
    float r0=row_sum[c0], r1=row_sum[c1], r2=row_sum[c2], r3=row_sum[c3];
    float w0=ew[j]  *(r0>0.f?rsqrtf(r0):0.f);
    float w1=ew[j+1]*(r1>0.f?rsqrtf(r1):0.f);
    float w2_=ew[j+2]*(r2>0.f?rsqrtf(r2):0.f);
    float w3=ew[j+3]*(r3>0.f?rsqrtf(r3):0.f);
    ushort4 p0 = ((const ushort4*)(proj + (size_t)c0*DD))[t];
    ushort4 p1 = ((const ushort4*)(proj + (size_t)c1*DD))[t];
    ushort4 p2 = ((const ushort4*)(proj + (size_t)c2*DD))[t];
    ushort4 p3 = ((const ushort4*)(proj + (size_t)c3*DD))[t];
    a0.x += w0*bf2f(p0.x); a0.y += w0*bf2f(p0.y); a0.z += w0*bf2f(p0.z); a0.w += w0*bf2f(p0.w);
    a1.x += w1*bf2f(p1.x); a1.y += w1*bf2f(p1.y); a1.z += w1*bf2f(p1.z); a1.w += w1*bf2f(p1.w);
    a2.x += w2_*bf2f(p2.x); a2.y += w2_*bf2f(p2.y); a2.z += w2_*bf2f(p2.z); a2.w += w2_*bf2f(p2.w);
    a3.x += w3*bf2f(p3.x); a3.y += w3*bf2f(p3.y); a3.z += w3*bf2f(p3.z); a3.w += w3*bf2f(p3.w);
  }
  for (; j<end; ++j){
    int c0=col[j];
    float r0=row_sum[c0];
    float w0=ew[j]*(r0>0.f?rsqrtf(r0):0.f);
    ushort4 p0 = ((const ushort4*)(proj + (size_t)c0*DD))[t];
    a0.x += w0*bf2f(p0.x); a0.y += w0*bf2f(p0.y); a0.z += w0*bf2f(p0.z); a0.w += w0*bf2f(p0.w);
  }
  a0.x = dim*(a0.x + a1.x + a2.x + a3.x);
  a0.y = dim*(a0.y + a1.y + a2.y + a3.y);
  a0.z = dim*(a0.z + a1.z + a2.z + a3.z);
  a0.w = dim*(a0.w + a1.w + a2.w + a3.w);
  const float* xrow;
  if (LAYER==0){
    xrow = (m < NL) ? xf0 + (size_t)m*DD
         : (m < 2*NL) ? xf1 + (size_t)(m-NL)*DD
         : xf2 + (size_t)(m-2*NL)*DD;
  } else {
    xrow = xf0 + (size_t)m*DD;
  }
  float4 xv = ((const float4*)xrow)[t];
  float ax = xv.x + a0.x, ay = xv.y + a0.y, az = xv.z + a0.z, aw = xv.w + a0.w;
  float mx = xv.x * a0.x, my = xv.y * a0.y, mz = xv.z * a0.z, mw = xv.w * a0.w;
  ushort4 ra, rm;
  ra.x=f2bf(ax); ra.y=f2bf(ay); ra.z=f2bf(az); ra.w=f2bf(aw);
  rm.x=f2bf(mx); rm.y=f2bf(my); rm.z=f2bf(mz); rm.w=f2bf(mw);
  size_t tileA = (size_t)((m>>4)*32 + (t>>3));
  int    off   = ((m&15) + ((t>>1)&3)*16)*8 + (t&1)*4;
  *(ushort4*)(P + tileA*512 + off)        = ra;
  *(ushort4*)(P + (tileA+16)*512 + off)   = rm;
}

extern "C" void kernel_launch(void* const* d_in, const int* in_sizes, int n_in,
                              void* d_out, int out_size, void* d_ws, size_t ws_size,
                              hipStream_t stream){
  const float* f0 = (const float*)d_in[0];
  const float* f1 = (const float*)d_in[1];
  const float* f2 = (const float*)d_in[2];
  const int*   ei = (const int*)d_in[3];
  const float* pw = (const float*)d_in[4];
  const float* w1 = (const float*)d_in[5];
  const float* b1 = (const float*)d_in[6];
  const float* w2 = (const float*)d_in[7];
  const float* b2 = (const float*)d_in[8];
  const float* W1_0 = (const float*)d_in[9];
  const float* W2_0 = (const float*)d_in[10];
  const float* W1_1 = (const float*)d_in[11];
  const float* W2_1 = (const float*)d_in[12];
  float* out = (float*)d_out;

  const int* src = ei;
  const int* tgt = ei + NE;

  char* base = (char*)d_ws;
  size_t o = 0;
  auto alloc = [&](size_t bytes)->char*{ char* p = base + o; o += (bytes + 1023) & ~size_t(1023); return p; };
  float* x1      = (float*)alloc((size_t)NN*DD*4);
  ushort* projbf = (ushort*)alloc((size_t)NN*DD*2);
  float* projS   = (float*)alloc((size_t)NN*SS*4);
  ushort* ABn    = (ushort*)alloc((size_t)NN*256*2);
  short* Apack1  = (short*)alloc((size_t)MT*16*1024);
  short* Apack2  = (short*)alloc((size_t)MT*32*1024);
  short* ShP     = (short*)alloc((size_t)MT*4*1024);
  short* BpF     = (short*)alloc((size_t)8*16*1024);
  short* Bpab    = (short*)alloc((size_t)16*4*1024);
  short* Bp10    = (short*)alloc((size_t)32*16*1024);
  short* Bp20    = (short*)alloc((size_t)32*32*1024);
  short* Bp11    = (short*)alloc((size_t)32*16*1024);
  short* Bp21    = (short*)alloc((size_t)32*32*1024);
  float* ew      = (float*)alloc(NE*4);
  float* row_sum = (float*)alloc(NN*4);
  int*   cnt     = (int*)alloc(NN*4);
  int*   fill    = (int*)alloc(NN*4);
  int*   row_ptr = (int*)alloc((NN+1)*4);
  int*   col     = (int*)alloc(NE*4);

  hipMemsetAsync(cnt, 0, NN*4, stream);

  // all packs + row_sum zero + src histogram in one dispatch
  k_packall<<<3120, 256, 0, stream>>>(f0,f1,f2,pw,w1,W1_0,W2_0,W1_1,W2_1,src,
                                      Apack1,BpF,Bp10,Bp20,Bp11,Bp21,Bpab,row_sum,cnt);
  k_scan<<<1, 1024, 0, stream>>>(cnt,row_ptr,fill);

  // front-end: shared = l2norm(feature@pw^T) (packed); [A|B] = shared@[W1a;W1b]^T
  k_gmm<0,0><<<1*72, 256, 0, stream>>>(Apack1, BpF, projS, NN, 128, 512);
  k_l2n<<<NN/4, 256, 0, stream>>>(projS, ShP);
  k_gmm<0,1><<<2*72, 256, 0, stream>>>(ShP, Bpab, ABn, NN, 256, 128);

  // edge weights + direct CSR scatter
  k_edge<<<2048, 256, 0, stream>>>(src,tgt,ABn,b1,w2,b2,row_ptr,fill,col,ew,row_sum);

  // layer 1
  k_gmm<0,1><<<4*72, 256, 0, stream>>>(Apack1, Bp10, projbf, NN, DD, DD);
  k_spmm_cat<0><<<NN, 128, 0, stream>>>(row_ptr, col, ew, row_sum, projbf, f0, f1, f2, Apack2);
  k_gmm<1,0><<<4*72, 256, 0, stream>>>(Apack2, Bp20, x1, NN, DD, 2*DD);
  // layer 2
  k_pack<<<MT*16/4, 256, 0, stream>>>(x1, Apack1, NN, DD, 16);
  k_gmm<0,1><<<4*72, 256, 0, stream>>>(Apack1, Bp11, projbf, NN, DD, DD);
  k_spmm_cat<1><<<NN, 128, 0, stream>>>(row_ptr, col, ew, row_sum, projbf, x1, nullptr, nullptr, Apack2);
  k_gmm<1,0><<<4*72, 256, 0, stream>>>(Apack2, Bp21, out, NN, DD, 2*DD);
}

// Round 12
// 319.320 us; speedup vs baseline: 1.0238x; 1.0238x over previous
//
#include <hip/hip_runtime.h>
#include <hip/hip_bf16.h>
#include <math.h>

#define NL 3000
#define NN 9000
#define NE 200000
#define DD 512
#define SS 128
#define MPAD 9088          // 71 * 128
#define MT   (MPAD/16)     // 568 m-tiles

typedef __attribute__((ext_vector_type(8))) short    bf16x8;
typedef __attribute__((ext_vector_type(8))) ushort   u16x8;
typedef __attribute__((ext_vector_type(4))) float    f32x4;

static __device__ __forceinline__ ushort f2bf(float f){
  unsigned u = __float_as_uint(f);
  return (ushort)((u + 0x7FFFu + ((u>>16)&1u)) >> 16);   // RNE
}
static __device__ __forceinline__ float bf2f(ushort u){
  return __uint_as_float(((unsigned)u)<<16);
}

// ================= merged pack kernel (+ src histogram + row_sum zero) =================
__global__ __launch_bounds__(256) void k_packall(const float* __restrict__ f0, const float* __restrict__ f1,
                        const float* __restrict__ f2, const float* __restrict__ pw,
                        const float* __restrict__ w1,
                        const float* __restrict__ W10, const float* __restrict__ W20,
                        const float* __restrict__ W11, const float* __restrict__ W21,
                        const int* __restrict__ src,
                        short* __restrict__ Ap1, short* __restrict__ BpF,
                        short* __restrict__ Bp10, short* __restrict__ Bp20,
                        short* __restrict__ Bp11, short* __restrict__ Bp21,
                        short* __restrict__ Bpab,
                        float* __restrict__ row_sum, int* __restrict__ cnt){
  int b = blockIdx.x;
  int lane = threadIdx.x & 63;
  if (b < 2272){
    int t = b*4 + (threadIdx.x>>6);
    int tm = t >> 4, tk = t & 15;
    int m = tm*16 + (lane&15);
    int k = tk*32 + (lane>>4)*8;
    float4 v0 = make_float4(0,0,0,0), v1 = v0;
    if (m < NN){
      const float* srow = (m < NL) ? f0 + (size_t)m*DD
                         : (m < 2*NL) ? f1 + (size_t)(m-NL)*DD
                         : f2 + (size_t)(m-2*NL)*DD;
      v0 = *(const float4*)(srow + k);
      v1 = *(const float4*)(srow + k + 4);
    }
    u16x8 r;
    r[0]=f2bf(v0.x); r[1]=f2bf(v0.y); r[2]=f2bf(v0.z); r[3]=f2bf(v0.w);
    r[4]=f2bf(v1.x); r[5]=f2bf(v1.y); r[6]=f2bf(v1.z); r[7]=f2bf(v1.w);
    *(u16x8*)(Ap1 + (size_t)t*512 + lane*8) = r;
  } else if (b < 3072){
    int t = (b-2272)*4 + (threadIdx.x>>6);   // 0..3199
    const float* X; short* P; int K, ntk, lt;
    if (t < 128)      { X=pw;  P=BpF;  K=512;  ntk=16; lt=t; }
    else if (t < 640) { X=W10; P=Bp10; K=512;  ntk=16; lt=t-128; }
    else if (t < 1664){ X=W20; P=Bp20; K=1024; ntk=32; lt=t-640; }
    else if (t < 2176){ X=W11; P=Bp11; K=512;  ntk=16; lt=t-1664; }
    else              { X=W21; P=Bp21; K=1024; ntk=32; lt=t-2176; }
    int tm = lt/ntk, tk = lt - tm*ntk;
    int m = tm*16 + (lane&15);
    int k = tk*32 + (lane>>4)*8;
    float4 v0 = *(const float4*)(X + (size_t)m*K + k);
    float4 v1 = *(const float4*)(X + (size_t)m*K + k + 4);
    u16x8 r;
    r[0]=f2bf(v0.x); r[1]=f2bf(v0.y); r[2]=f2bf(v0.z); r[3]=f2bf(v0.w);
    r[4]=f2bf(v1.x); r[5]=f2bf(v1.y); r[6]=f2bf(v1.z); r[7]=f2bf(v1.w);
    *(u16x8*)(P + (size_t)lt*512 + lane*8) = r;
  } else if (b < 3088){
    int t = (b-3072)*4 + (threadIdx.x>>6);   // 64 tiles: tn*4+tk
    int tn = t >> 2, tk = t & 3;
    int n = tn*16 + (lane&15);
    int k = tk*32 + (lane>>4)*8;
    const float* sp = (n<128) ? (w1 + (size_t)n*256 + k) : (w1 + (size_t)(n-128)*256 + 128 + k);
    float4 v0 = *(const float4*)sp;
    float4 v1 = *(const float4*)(sp+4);
    u16x8 r;
    r[0]=f2bf(v0.x); r[1]=f2bf(v0.y); r[2]=f2bf(v0.z); r[3]=f2bf(v0.w);
    r[4]=f2bf(v1.x); r[5]=f2bf(v1.y); r[6]=f2bf(v1.z); r[7]=f2bf(v1.w);
    *(u16x8*)(Bpab + (size_t)t*512 + lane*8) = r;
  } else {
    int idx = (b-3088)*256 + threadIdx.x;    // 8192 threads
    for (int i=idx; i<NN; i+=8192) row_sum[i]=0.f;
    for (int e=idx; e<NE; e+=8192) atomicAdd(&cnt[src[e]],1);
  }
}

// ---------------- pack fp32 (M,K) row-major -> MFMA-tile bf16 layout ----------------
__global__ __launch_bounds__(256) void k_pack(const float* __restrict__ X, short* __restrict__ P,
                                              int M, int K, int nTilesK){
  int t = blockIdx.x*4 + (threadIdx.x>>6);
  int lane = threadIdx.x & 63;
  int tm = t / nTilesK, tk = t - tm*nTilesK;
  int m = tm*16 + (lane&15);
  int k = tk*32 + (lane>>4)*8;
  float4 v0 = make_float4(0,0,0,0), v1 = v0;
  if (m < M){
    v0 = *(const float4*)(X + (size_t)m*K + k);
    v1 = *(const float4*)(X + (size_t)m*K + k + 4);
  }
  u16x8 r;
  r[0]=f2bf(v0.x); r[1]=f2bf(v0.y); r[2]=f2bf(v0.z); r[3]=f2bf(v0.w);
  r[4]=f2bf(v1.x); r[5]=f2bf(v1.y); r[6]=f2bf(v1.z); r[7]=f2bf(v1.w);
  *(u16x8*)(P + (size_t)t*512 + lane*8) = r;
}

// ================= MFMA GEMM, barrier-free, 128x64 tile, XCD-aware remap =================
// 1-D grid, (N/64)*72 blocks. r=l&7, tt=l>>3, q=tt%9, x=tt/9, y=8q+r (skip y>=71).
template<int ACT, int OBF>
__global__ __launch_bounds__(256) void k_gmm(const short* __restrict__ Ap, const short* __restrict__ Bp,
                                             void* __restrict__ Cv, int M, int N, int K){
  int l = blockIdx.x;
  int rr = l & 7, tt = l >> 3;
  int q = tt % 9, x = tt / 9;
  int y = q*8 + rr;
  if (y >= 71) return;
  int lane = threadIdx.x & 63, wave = threadIdx.x >> 6;
  int ktiles = K >> 5;
  int bm = y*128 + wave*32;
  int bn = x*64;
  const bf16x8* a0 = (const bf16x8*)(Ap + ((size_t)((bm>>4)  ) * ktiles)*512 + lane*8);
  const bf16x8* a1 = (const bf16x8*)(Ap + ((size_t)((bm>>4)+1) * ktiles)*512 + lane*8);
  const bf16x8* b0 = (const bf16x8*)(Bp + ((size_t)((bn>>4)  ) * ktiles)*512 + lane*8);
  const bf16x8* b1 = (const bf16x8*)(Bp + ((size_t)((bn>>4)+1) * ktiles)*512 + lane*8);
  const bf16x8* b2 = (const bf16x8*)(Bp + ((size_t)((bn>>4)+2) * ktiles)*512 + lane*8);
  const bf16x8* b3 = (const bf16x8*)(Bp + ((size_t)((bn>>4)+3) * ktiles)*512 + lane*8);
  f32x4 acc[2][4];
  #pragma unroll
  for (int i=0;i<2;++i)
    #pragma unroll
    for (int j=0;j<4;++j) acc[i][j] = (f32x4){0.f,0.f,0.f,0.f};

  for (int kt=0; kt<ktiles; ++kt){
    int off = kt*64;
    bf16x8 A0 = a0[off], A1 = a1[off];
    bf16x8 B0 = b0[off], B1 = b1[off], B2 = b2[off], B3 = b3[off];
    acc[0][0] = __builtin_amdgcn_mfma_f32_16x16x32_bf16(A0, B0, acc[0][0], 0,0,0);
    acc[0][1] = __builtin_amdgcn_mfma_f32_16x16x32_bf16(A0, B1, acc[0][1], 0,0,0);
    acc[0][2] = __builtin_amdgcn_mfma_f32_16x16x32_bf16(A0, B2, acc[0][2], 0,0,0);
    acc[0][3] = __builtin_amdgcn_mfma_f32_16x16x32_bf16(A0, B3, acc[0][3], 0,0,0);
    acc[1][0] = __builtin_amdgcn_mfma_f32_16x16x32_bf16(A1, B0, acc[1][0], 0,0,0);
    acc[1][1] = __builtin_amdgcn_mfma_f32_16x16x32_bf16(A1, B1, acc[1][1], 0,0,0);
    acc[1][2] = __builtin_amdgcn_mfma_f32_16x16x32_bf16(A1, B2, acc[1][2], 0,0,0);
    acc[1][3] = __builtin_amdgcn_mfma_f32_16x16x32_bf16(A1, B3, acc[1][3], 0,0,0);
  }
  int colo = lane & 15;
  int rowo = (lane >> 4) * 4;
  #pragma unroll
  for (int mi=0; mi<2; ++mi){
    #pragma unroll
    for (int r=0; r<4; ++r){
      int row = bm + mi*16 + rowo + r;
      if (row < M){
        #pragma unroll
        for (int ni=0; ni<4; ++ni){
          float v = acc[mi][ni][r];
          if (ACT) v = v>0.f ? v : 0.01f*v;
          int cidx = bn + ni*16 + colo;
          if (OBF) ((ushort*)Cv)[(size_t)row*N + cidx] = f2bf(v);
          else     ((float*) Cv)[(size_t)row*N + cidx] = v;
        }
      }
    }
  }
}

// ---------------- l2norm rows of (NN,128) fp32 -> packed MFMA tiles (K=128) ----------------
__global__ __launch_bounds__(256) void k_l2n(const float* __restrict__ X, short* __restrict__ ShP){
  int lane = threadIdx.x & 63, wave = threadIdx.x >> 6;
  int m = blockIdx.x*4 + wave;
  float2 v = ((const float2*)(X + (size_t)m*SS))[lane];
  float ss = v.x*v.x + v.y*v.y;
  #pragma unroll
  for (int o=32;o>0;o>>=1) ss += __shfl_xor(ss, o);
  float inv = 1.f / fmaxf(sqrtf(ss), 1e-12f);
  int k = 2*lane;
  int tIdx = (m>>4)*4 + (k>>5);
  int pos  = ((m&15) + ((k>>3)&3)*16)*8 + (k&7);
  ushort2 r; r.x = f2bf(v.x*inv); r.y = f2bf(v.y*inv);
  *(ushort2*)(ShP + (size_t)tIdx*512 + pos) = r;
}

// ---------------- per-edge weight + direct CSR scatter: 4 edges/wave, 16 lanes/edge ----------------
__global__ __launch_bounds__(256) void k_edge(const int* __restrict__ src, const int* __restrict__ tgt,
                      const ushort* __restrict__ AB,
                      const float* __restrict__ b1, const float* __restrict__ w2,
                      const float* __restrict__ b2p,
                      const int* __restrict__ row_ptr, int* __restrict__ fill,
                      int* __restrict__ col, float* __restrict__ ewC,
                      float* __restrict__ row_sum){
  int lane = threadIdx.x & 63;
  int p = lane & 15, g = lane >> 4;
  int wid = blockIdx.x*(blockDim.x>>6) + (threadIdx.x>>6);
  int nw  = gridDim.x*(blockDim.x>>6);
  float4 b1a = ((const float4*)b1)[p*2], b1b = ((const float4*)b1)[p*2+1];
  float4 w2a = ((const float4*)w2)[p*2], w2b = ((const float4*)w2)[p*2+1];
  float bb[8] = {b1a.x,b1a.y,b1a.z,b1a.w,b1b.x,b1b.y,b1b.z,b1b.w};
  float ww[8] = {w2a.x,w2a.y,w2a.z,w2a.w,w2b.x,w2b.y,w2b.z,w2b.w};
  float b2 = b2p[0];
  for (int e = wid*4+g; e < NE; e += nw*4){
    int s = src[e], tg_ = tgt[e];
    u16x8 av = *(const u16x8*)(AB + (size_t)s*256 + p*8);
    u16x8 bv = *(const u16x8*)(AB + (size_t)tg_*256 + 128 + p*8);
    float acc = 0.f;
    #pragma unroll
    for (int i=0;i<8;++i){
      float h = bf2f(av[i]) + bf2f(bv[i]) + bb[i];
      h = h>0.f ? h : 0.01f*h;
      acc += h*ww[i];
    }
    acc += __shfl_xor(acc,1); acc += __shfl_xor(acc,2);
    acc += __shfl_xor(acc,4); acc += __shfl_xor(acc,8);
    if (p==0){
      float wgt = 1.f/(1.f+expf(-(acc+b2)));
      int pos = atomicAdd(&fill[s],1);
      int idx = row_ptr[s]+pos;
      col[idx]=tg_;
      ewC[idx]=wgt;
      atomicAdd(&row_sum[s], wgt);
    }
  }
}

// ---------------- shuffle-based scan: cnt -> row_ptr ; zero fill ----------------
__global__ __launch_bounds__(1024) void k_scan(const int* __restrict__ cnt,
                      int* __restrict__ row_ptr, int* __restrict__ fill){
  __shared__ int wsum[16];
  int t = threadIdx.x;
  int lane = t & 63, wid = t >> 6;
  const int CH = 9;                       // 1024*9 = 9216 >= 9000
  int base = t*CH;
  int v[CH]; int s = 0;
  #pragma unroll
  for (int i=0;i<CH;++i){
    int idx = base+i;
    v[i] = (idx<NN) ? cnt[idx] : 0;
    s += v[i];
  }
  int ps = s;
  #pragma unroll
  for (int o=1;o<64;o<<=1){
    int x = __shfl_up(ps, o);
    if (lane >= o) ps += x;
  }
  if (lane==63) wsum[wid] = ps;
  __syncthreads();
  if (wid==0){
    int wv = (lane<16)? wsum[lane] : 0;
    #pragma unroll
    for (int o=1;o<16;o<<=1){
      int x = __shfl_up(wv, o);
      if (lane>=o) wv += x;
    }
    if (lane<16) wsum[lane]=wv;
  }
  __syncthreads();
  int prefix = (wid>0 ? wsum[wid-1] : 0) + (ps - s);
  #pragma unroll
  for (int i=0;i<CH;++i){
    int idx = base+i;
    if (idx<NN){
      row_ptr[idx] = prefix;
      fill[idx] = 0;
      prefix += v[i];
    }
  }
  if (t==1023) row_ptr[NN] = wsum[15];
}

// ---------------- fused SpMM + cat + pack (dinv on the fly) ----------------
template<int LAYER>
__global__ __launch_bounds__(128) void k_spmm_cat(const int* __restrict__ row_ptr, const int* __restrict__ col,
                     const float* __restrict__ ew, const float* __restrict__ row_sum,
                     const ushort* __restrict__ proj,
                     const float* __restrict__ xf0, const float* __restrict__ xf1,
                     const float* __restrict__ xf2,
                     short* __restrict__ P){
  int m = blockIdx.x, t = threadIdx.x;
  int beg = row_ptr[m], end = row_ptr[m+1];
  float rsm = row_sum[m];
  float dim = rsm>0.f ? rsqrtf(rsm) : 0.f;
  float4 a0 = make_float4(0,0,0,0), a1 = a0, a2 = a0, a3 = a0;
  int j = beg;
  for (; j+4<=end; j+=4){
    int c0=col[j], c1=col[j+1], c2=col[j+2], c3=col[j+3];
    float r0=row_sum[c0], r1=row_sum[c1], r2=row_sum[c2], r3=row_sum[c3];
    float w0=ew[j]  *(r0>0.f?rsqrtf(r0):0.f);
    float w1=ew[j+1]*(r1>0.f?rsqrtf(r1):0.f);
    float w2_=ew[j+2]*(r2>0.f?rsqrtf(r2):0.f);
    float w3=ew[j+3]*(r3>0.f?rsqrtf(r3):0.f);
    ushort4 p0 = ((const ushort4*)(proj + (size_t)c0*DD))[t];
    ushort4 p1 = ((const ushort4*)(proj + (size_t)c1*DD))[t];
    ushort4 p2 = ((const ushort4*)(proj + (size_t)c2*DD))[t];
    ushort4 p3 = ((const ushort4*)(proj + (size_t)c3*DD))[t];
    a0.x += w0*bf2f(p0.x); a0.y += w0*bf2f(p0.y); a0.z += w0*bf2f(p0.z); a0.w += w0*bf2f(p0.w);
    a1.x += w1*bf2f(p1.x); a1.y += w1*bf2f(p1.y); a1.z += w1*bf2f(p1.z); a1.w += w1*bf2f(p1.w);
    a2.x += w2_*bf2f(p2.x); a2.y += w2_*bf2f(p2.y); a2.z += w2_*bf2f(p2.z); a2.w += w2_*bf2f(p2.w);
    a3.x += w3*bf2f(p3.x); a3.y += w3*bf2f(p3.y); a3.z += w3*bf2f(p3.z); a3.w += w3*bf2f(p3.w);
  }
  for (; j<end; ++j){
    int c0=col[j];
    float r0=row_sum[c0];
    float w0=ew[j]*(r0>0.f?rsqrtf(r0):0.f);
    ushort4 p0 = ((const ushort4*)(proj + (size_t)c0*DD))[t];
    a0.x += w0*bf2f(p0.x); a0.y += w0*bf2f(p0.y); a0.z += w0*bf2f(p0.z); a0.w += w0*bf2f(p0.w);
  }
  a0.x = dim*(a0.x + a1.x + a2.x + a3.x);
  a0.y = dim*(a0.y + a1.y + a2.y + a3.y);
  a0.z = dim*(a0.z + a1.z + a2.z + a3.z);
  a0.w = dim*(a0.w + a1.w + a2.w + a3.w);
  const float* xrow;
  if (LAYER==0){
    xrow = (m < NL) ? xf0 + (size_t)m*DD
         : (m < 2*NL) ? xf1 + (size_t)(m-NL)*DD
         : xf2 + (size_t)(m-2*NL)*DD;
  } else {
    xrow = xf0 + (size_t)m*DD;
  }
  float4 xv = ((const float4*)xrow)[t];
  float ax = xv.x + a0.x, ay = xv.y + a0.y, az = xv.z + a0.z, aw = xv.w + a0.w;
  float mx = xv.x * a0.x, my = xv.y * a0.y, mz = xv.z * a0.z, mw = xv.w * a0.w;
  ushort4 ra, rm;
  ra.x=f2bf(ax); ra.y=f2bf(ay); ra.z=f2bf(az); ra.w=f2bf(aw);
  rm.x=f2bf(mx); rm.y=f2bf(my); rm.z=f2bf(mz); rm.w=f2bf(mw);
  size_t tileA = (size_t)((m>>4)*32 + (t>>3));
  int    off   = ((m&15) + ((t>>1)&3)*16)*8 + (t&1)*4;
  *(ushort4*)(P + tileA*512 + off)        = ra;
  *(ushort4*)(P + (tileA+16)*512 + off)   = rm;
}

extern "C" void kernel_launch(void* const* d_in, const int* in_sizes, int n_in,
                              void* d_out, int out_size, void* d_ws, size_t ws_size,
                              hipStream_t stream){
  const float* f0 = (const float*)d_in[0];
  const float* f1 = (const float*)d_in[1];
  const float* f2 = (const float*)d_in[2];
  const int*   ei = (const int*)d_in[3];
  const float* pw = (const float*)d_in[4];
  const float* w1 = (const float*)d_in[5];
  const float* b1 = (const float*)d_in[6];
  const float* w2 = (const float*)d_in[7];
  const float* b2 = (const float*)d_in[8];
  const float* W1_0 = (const float*)d_in[9];
  const float* W2_0 = (const float*)d_in[10];
  const float* W1_1 = (const float*)d_in[11];
  const float* W2_1 = (const float*)d_in[12];
  float* out = (float*)d_out;

  const int* src = ei;
  const int* tgt = ei + NE;

  char* base = (char*)d_ws;
  size_t o = 0;
  auto alloc = [&](size_t bytes)->char*{ char* p = base + o; o += (bytes + 1023) & ~size_t(1023); return p; };
  float* x1      = (float*)alloc((size_t)NN*DD*4);
  ushort* projbf = (ushort*)alloc((size_t)NN*DD*2);
  float* projS   = (float*)alloc((size_t)NN*SS*4);
  ushort* ABn    = (ushort*)alloc((size_t)NN*256*2);
  short* Apack1  = (short*)alloc((size_t)MT*16*1024);
  short* Apack2  = (short*)alloc((size_t)MT*32*1024);
  short* ShP     = (short*)alloc((size_t)MT*4*1024);
  short* BpF     = (short*)alloc((size_t)8*16*1024);
  short* Bpab    = (short*)alloc((size_t)16*4*1024);
  short* Bp10    = (short*)alloc((size_t)32*16*1024);
  short* Bp20    = (short*)alloc((size_t)32*32*1024);
  short* Bp11    = (short*)alloc((size_t)32*16*1024);
  short* Bp21    = (short*)alloc((size_t)32*32*1024);
  float* ew      = (float*)alloc(NE*4);
  float* row_sum = (float*)alloc(NN*4);
  int*   cnt     = (int*)alloc(NN*4);
  int*   fill    = (int*)alloc(NN*4);
  int*   row_ptr = (int*)alloc((NN+1)*4);
  int*   col     = (int*)alloc(NE*4);

  hipMemsetAsync(cnt, 0, NN*4, stream);

  // all packs + row_sum zero + src histogram in one dispatch
  k_packall<<<3120, 256, 0, stream>>>(f0,f1,f2,pw,w1,W1_0,W2_0,W1_1,W2_1,src,
                                      Apack1,BpF,Bp10,Bp20,Bp11,Bp21,Bpab,row_sum,cnt);
  k_scan<<<1, 1024, 0, stream>>>(cnt,row_ptr,fill);

  // front-end: shared = l2norm(feature@pw^T) (packed); [A|B] = shared@[W1a;W1b]^T
  k_gmm<0,0><<<2*72, 256, 0, stream>>>(Apack1, BpF, projS, NN, 128, 512);
  k_l2n<<<NN/4, 256, 0, stream>>>(projS, ShP);
  k_gmm<0,1><<<4*72, 256, 0, stream>>>(ShP, Bpab, ABn, NN, 256, 128);

  // edge weights + direct CSR scatter
  k_edge<<<2048, 256, 0, stream>>>(src,tgt,ABn,b1,w2,b2,row_ptr,fill,col,ew,row_sum);

  // layer 1
  k_gmm<0,1><<<8*72, 256, 0, stream>>>(Apack1, Bp10, projbf, NN, DD, DD);
  k_spmm_cat<0><<<NN, 128, 0, stream>>>(row_ptr, col, ew, row_sum, projbf, f0, f1, f2, Apack2);
  k_gmm<1,0><<<8*72, 256, 0, stream>>>(Apack2, Bp20, x1, NN, DD, 2*DD);
  // layer 2
  k_pack<<<MT*16/4, 256, 0, stream>>>(x1, Apack1, NN, DD, 16);
  k_gmm<0,1><<<8*72, 256, 0, stream>>>(Apack1, Bp11, projbf, NN, DD, DD);
  k_spmm_cat<1><<<NN, 128, 0, stream>>>(row_ptr, col, ew, row_sum, projbf, x1, nullptr, nullptr, Apack2);
  k_gmm<1,0><<<8*72, 256, 0, stream>>>(Apack2, Bp21, out, NN, DD, 2*DD);
}